// Round 20
// baseline (2998.136 us; speedup 1.0000x reference)
//
#include <hip/hip_runtime.h>
#include <hip/hip_bf16.h>

// GRU: B=64, S=512, I=1024, H=1024, fp32 in/out, final h only.
// Round 20 = round-19 (green: 4-phase interleave, preload@phase-start,
// per-wave vmcnt(0) BEFORE sync#1, W in regs, plds dbuf, no barrier#3)
// + per-wave autonomous readiness check:
//   - flag preload replicated on ALL 4 waves (each wave loads all 64 flags)
//   - each wave launders+checks its own copy and polls independently on miss
//   - barrier #2 DELETED (no cross-wave verdict release needed)
// Soundness: aff issue is control-dependent on the wave's own flag
// observation; queues stay uniform (all waves issue preload; pre-sync
// vmcnt(0) resets all); max skew = 1 phase (next sync#1 blocks), so the
// plds 2-phase reuse argument from r19 still holds.

#define B_ 64
#define S_ 512
#define H_ 1024

typedef __bf16 bf16;
typedef __bf16 bf16x8 __attribute__((ext_vector_type(8)));
typedef float  f32x4  __attribute__((ext_vector_type(4)));
typedef unsigned int u32;

// ---- asm helpers (verbatim rounds 2/6/8/12/13/16/19) -----------------------
__device__ __forceinline__ void ld_cc16(const bf16* p, f32x4* dst) {
  asm volatile("global_load_dwordx4 %0, %1, off sc0 sc1" : "=v"(*dst) : "v"(p));
}
__device__ __forceinline__ void ld_u16(const bf16* p, u32* dst) {
  asm volatile("global_load_ushort %0, %1, off" : "=v"(*dst) : "v"(p));
}
__device__ __forceinline__ void st_cc16(bf16* p, u32 bits) {
  asm volatile("global_store_short %0, %1, off sc0 sc1" :: "v"(p), "v"(bits) : "memory");
}

// ---------------- init: zero flags, pack h0 into hbuf[0] --------------------
__global__ void k_init(const float* __restrict__ h0, bf16* __restrict__ hbuf,
                       u32* __restrict__ flags) {
  int t = blockIdx.x * 256 + threadIdx.x;
  if (t < 4096) flags[t] = 0u;
  if (t < B_ * H_) {
    int b = t >> 10, j = t & 1023;
    hbuf[((size_t)((j >> 3) * 64 + b)) * 8 + (j & 7)] = (bf16)h0[t];
  }
}

// ---------------- gi GEMM: [32768,1024] x [1024,3072] -> bf16 ---------------
__global__ __launch_bounds__(256) void k_gemm(const float* __restrict__ X,
                                              const float* __restrict__ W,
                                              const float* __restrict__ bias,
                                              bf16* __restrict__ gi) {
  __shared__ bf16 As[128 * 40];
  __shared__ bf16 Bs[128 * 40];
  const int tid = threadIdx.x;
  // XCD-aware swizzle: 6144 blocks, 8 XCDs, 768 per XCD (bijective, chunked)
  const int bid = (blockIdx.x % 8) * 768 + (blockIdx.x / 8);
  const int bidn = bid % 24, bidm = bid / 24;
  const int row = tid >> 1, half = tid & 1;
  const float* ax = X + (size_t)(bidm * 128 + row) * 1024 + half * 16;
  const float* bw = W + (size_t)(bidn * 128 + row) * 1024 + half * 16;
  const int lane = tid & 63, wave = tid >> 6;
  const int wm = wave >> 1, wn = wave & 1;

  f32x4 acc[4][4];
#pragma unroll
  for (int i = 0; i < 4; ++i)
#pragma unroll
    for (int j = 0; j < 4; ++j) acc[i][j] = (f32x4){0.f, 0.f, 0.f, 0.f};

  for (int ks = 0; ks < 32; ++ks) {
    {
      const float* pa = ax + ks * 32;
      f32x4 a0 = *(const f32x4*)(pa);
      f32x4 a1 = *(const f32x4*)(pa + 4);
      f32x4 a2 = *(const f32x4*)(pa + 8);
      f32x4 a3 = *(const f32x4*)(pa + 12);
      bf16x8 v0, v1;
#pragma unroll
      for (int i = 0; i < 4; ++i) {
        v0[i] = (bf16)a0[i]; v0[4 + i] = (bf16)a1[i];
        v1[i] = (bf16)a2[i]; v1[4 + i] = (bf16)a3[i];
      }
      *(bf16x8*)&As[row * 40 + half * 16]     = v0;
      *(bf16x8*)&As[row * 40 + half * 16 + 8] = v1;

      const float* pb = bw + ks * 32;
      f32x4 b0 = *(const f32x4*)(pb);
      f32x4 b1 = *(const f32x4*)(pb + 4);
      f32x4 b2 = *(const f32x4*)(pb + 8);
      f32x4 b3 = *(const f32x4*)(pb + 12);
#pragma unroll
      for (int i = 0; i < 4; ++i) {
        v0[i] = (bf16)b0[i]; v0[4 + i] = (bf16)b1[i];
        v1[i] = (bf16)b2[i]; v1[4 + i] = (bf16)b3[i];
      }
      *(bf16x8*)&Bs[row * 40 + half * 16]     = v0;
      *(bf16x8*)&Bs[row * 40 + half * 16 + 8] = v1;
    }
    __syncthreads();
    bf16x8 af[4], bfr[4];
#pragma unroll
    for (int mi = 0; mi < 4; ++mi)
      af[mi] = *(const bf16x8*)&As[(wm * 64 + mi * 16 + (lane & 15)) * 40 + (lane >> 4) * 8];
#pragma unroll
    for (int ni = 0; ni < 4; ++ni)
      bfr[ni] = *(const bf16x8*)&Bs[(wn * 64 + ni * 16 + (lane & 15)) * 40 + (lane >> 4) * 8];
#pragma unroll
    for (int mi = 0; mi < 4; ++mi)
#pragma unroll
      for (int ni = 0; ni < 4; ++ni)
        acc[mi][ni] = __builtin_amdgcn_mfma_f32_16x16x32_bf16(af[mi], bfr[ni], acc[mi][ni], 0, 0, 0);
    __syncthreads();
  }

  float bv[4];
#pragma unroll
  for (int ni = 0; ni < 4; ++ni)
    bv[ni] = bias[bidn * 128 + wn * 64 + ni * 16 + (lane & 15)];
#pragma unroll
  for (int mi = 0; mi < 4; ++mi)
#pragma unroll
    for (int ni = 0; ni < 4; ++ni)
#pragma unroll
      for (int r = 0; r < 4; ++r) {
        int grow = bidm * 128 + wm * 64 + mi * 16 + (lane >> 4) * 4 + r;
        int gcol = bidn * 128 + wn * 64 + ni * 16 + (lane & 15);
        gi[(size_t)grow * 3072 + gcol] = (bf16)(acc[mi][ni][r] + bv[ni]);
      }
}

// ---------------- persistent recurrent kernel (r19 + per-wave check) --------
// Per phase (grp,t):
//   vmcnt(4) [drains aff8] -> ISSUE flag preload (ALL waves) -> 24 MFMA
//   -> plds[grp&1] -> per-wave vmcnt(0) -> syncthreads(#1) -> signal prev
//   -> EACH WAVE: launder+check own preload (poll on miss) -> refill
//   -> gates (read plds[grp&1]) -> h-store    [barriers #2 and #3 deleted]
__global__ __launch_bounds__(256, 1) void k_rnn(
    const float* __restrict__ h0, const float* __restrict__ Whh,
    const float* __restrict__ bhh, const bf16* __restrict__ gi,
    bf16* __restrict__ hbuf, float* __restrict__ out, u32* __restrict__ flags) {
  __shared__ bf16 wlds[128 * 49 * 8];   // staging; K-loop never reads it
  __shared__ float plds[2 * 3072];      // double-buffered by grp parity
  __shared__ float hold[4][256];        // f32 local h per group

  const int tid = threadIdx.x;
  const int Q = blockIdx.x;                // unit block
  const int lane = tid & 63, wave = tid >> 6;
  const int b = tid >> 4, u = tid & 15;

  for (int idx = tid; idx < 48 * 128; idx += 256) {
    int c = idx % 48, k8 = idx / 48;
    int ga = c >> 4, un = c & 15;
    const float* src = Whh + (size_t)(ga * 1024 + Q * 16 + un) * 1024 + k8 * 8;
    bf16x8 v;
#pragma unroll
    for (int e = 0; e < 8; ++e) v[e] = (bf16)src[e];
    *(bf16x8*)&wlds[(size_t)(k8 * 49 + c) * 8] = v;
  }
#pragma unroll
  for (int g = 0; g < 4; ++g)
    hold[g][tid] = h0[(size_t)(g * 16 + b) * 1024 + Q * 16 + u];
  const float bh0 = bhh[Q * 16 + u];
  const float bh1 = bhh[1024 + Q * 16 + u];
  const float bh2 = bhh[2048 + Q * 16 + u];

  const bf16* giB = gi + (size_t)b * (512 * 3072) + Q * 16 + u;
  const size_t GSTR = (size_t)16 * 512 * 3072;
  const int aoff0 = ((wave * 32 + (lane >> 4)) * 64 + (lane & 15)) * 8;
  const int jj = Q * 16 + u;
  const int hoff0 = ((jj >> 3) * 64 + b) * 8 + (jj & 7);

  __syncthreads();

  // W fragments -> registers (proven round 8)
  bf16x8 wreg[24];
#pragma unroll
  for (int kk = 0; kk < 8; ++kk) {
    int k8 = wave * 32 + kk * 4 + (lane >> 4);
    const bf16* wb = &wlds[(size_t)(k8 * 49 + (lane & 15)) * 8];
    wreg[kk * 3 + 0] = *(const bf16x8*)(wb);
    wreg[kk * 3 + 1] = *(const bf16x8*)(wb + 16 * 8);
    wreg[kk * 3 + 2] = *(const bf16x8*)(wb + 32 * 8);
  }

  f32x4 aff[8];
  u32 gc0, gc1, gc2, gn0, gn1, gn2;
  {
    const bf16* ab = hbuf + aoff0;   // buffer 0, grp 0
#pragma unroll
    for (int kk = 0; kk < 8; ++kk) ld_cc16(ab + kk * 2048, &aff[kk]);
    ld_u16(giB, &gc0); ld_u16(giB + 1024, &gc1); ld_u16(giB + 2048, &gc2);
  }

  int bad = 0;
  for (int t = 0; t < 512; ++t) {
    bf16* curb = hbuf + (size_t)(t & 1) * 65536;
    bf16* nxtb = hbuf + (size_t)((t & 1) ^ 1) * 65536;
    for (int grp = 0; grp < 4; ++grp) {
      const int pb = (grp & 1) * 3072;   // plds buffer for this phase
      if (t == 0 && grp == 0) { asm volatile("s_waitcnt vmcnt(0)" ::: "memory"); }
      else                    { asm volatile("s_waitcnt vmcnt(4)" ::: "memory"); }
      __builtin_amdgcn_sched_barrier(0);

      // preload at phase start — ALL waves (each covers all 64 producer WGs)
      const bool has_next = !(t == 511 && grp == 3);
      const int ng = (grp + 1) & 3;
      const u32 tn = (u32)((grp < 3) ? t : t + 1);
      u32 fpre = 0xFFFFFFFFu;
      if (has_next && tn) {
        const u32* fp = flags + (ng * 64 + lane) * 16;
        asm volatile("global_load_dword %0, %1, off sc0 sc1" : "=v"(fpre) : "v"(fp));
      }

      f32x4 acc0 = (f32x4){0.f,0.f,0.f,0.f};
      f32x4 acc1 = (f32x4){0.f,0.f,0.f,0.f};
      f32x4 acc2 = (f32x4){0.f,0.f,0.f,0.f};
#pragma unroll
      for (int kk = 0; kk < 8; ++kk) {
        bf16x8 a = __builtin_bit_cast(bf16x8, aff[kk]);
        acc0 = __builtin_amdgcn_mfma_f32_16x16x32_bf16(a, wreg[kk * 3 + 0], acc0, 0, 0, 0);
        acc1 = __builtin_amdgcn_mfma_f32_16x16x32_bf16(a, wreg[kk * 3 + 1], acc1, 0, 0, 0);
        acc2 = __builtin_amdgcn_mfma_f32_16x16x32_bf16(a, wreg[kk * 3 + 2], acc2, 0, 0, 0);
      }
      {
        int prow = wave * 16 + (lane >> 4) * 4;
#pragma unroll
        for (int r = 0; r < 4; ++r) {
          plds[pb + (prow + r) * 48 + (lane & 15)]      = acc0[r];
          plds[pb + (prow + r) * 48 + 16 + (lane & 15)] = acc1[r];
          plds[pb + (prow + r) * 48 + 32 + (lane & 15)] = acc2[r];
        }
      }
      // r12 invariant: per-wave drain BEFORE the barrier (store, gi, preload)
      asm volatile("s_waitcnt vmcnt(0)" ::: "memory");
      __builtin_amdgcn_sched_barrier(0);
      __syncthreads();   // #1: all waves drained => deferred signal is sound

      {
        int sg = (grp + 3) & 3;
        int st_ = (grp == 0) ? t - 1 : t;
        if (tid == 0 && st_ >= 0 && st_ < 511)
          __hip_atomic_store(&flags[(sg * 64 + Q) * 16], (u32)(st_ + 1),
                             __ATOMIC_RELAXED, __HIP_MEMORY_SCOPE_AGENT);
        // per-wave autonomous check: each wave validates its own copy and
        // proceeds to its refill without waiting for sibling waves.
        if (has_next && tn) {
          asm volatile("" : "+v"(fpre));   // launder: order after the drain
          if (!__all(fpre >= tn)) {
            const u32* fp = flags + (ng * 64 + lane) * 16;
            int guard = 0;
            while (1) {
              u32 f = __hip_atomic_load(fp, __ATOMIC_RELAXED,
                                        __HIP_MEMORY_SCOPE_AGENT);
              if (__all(f >= tn)) break;
              if (++guard > (1 << 16)) { bad = 1; break; }
              __builtin_amdgcn_s_sleep(1);
            }
          }
        }
      }
      // barrier #2 deleted: refill is gated by this wave's own check.

      if (has_next) {
        const bf16* ab = ((grp < 3) ? curb : nxtb) + aoff0 + ng * 128;
#pragma unroll
        for (int kk = 0; kk < 8; ++kk) ld_cc16(ab + kk * 2048, &aff[kk]);
        int ntp = (grp < 3) ? t : t + 1;
        const bf16* p = giB + (size_t)ng * GSTR + (size_t)ntp * 3072;
        ld_u16(p, &gn0); ld_u16(p + 1024, &gn1); ld_u16(p + 2048, &gn2);
      }

      float ghr = bh0, ghz = bh1, ghn = bh2;
#pragma unroll
      for (int w = 0; w < 4; ++w) {
        ghr += plds[pb + w * 768 + b * 48 + u];
        ghz += plds[pb + w * 768 + b * 48 + 16 + u];
        ghn += plds[pb + w * 768 + b * 48 + 32 + u];
      }
      float gir = __builtin_bit_cast(float, gc0 << 16);
      float giz = __builtin_bit_cast(float, gc1 << 16);
      float gin = __builtin_bit_cast(float, gc2 << 16);
      float rg = 1.f / (1.f + __expf(-(gir + ghr)));
      float zg = 1.f / (1.f + __expf(-(giz + ghz)));
      float e2 = __expf(2.f * (gin + rg * ghn));
      float tng = 1.f - 2.f / (e2 + 1.f);
      float hnew = (1.f - zg) * tng + zg * hold[grp][tid];
      hold[grp][tid] = hnew;
      if (t == 511) {
        if (bad) hnew = 12345.0f;   // stall signature
        out[(size_t)(grp * 16 + b) * 1024 + jj] = hnew;
      } else {
        unsigned short hb = __builtin_bit_cast(unsigned short, (bf16)hnew);
        st_cc16(nxtb + hoff0 + grp * 128, (u32)hb);
      }
      gc0 = gn0; gc1 = gn1; gc2 = gn2;
      // barrier #3 deleted (r19): next phase writes the other plds buffer;
      // the 2-phase-distant reuse is fenced by the intervening sync#1.
    }
  }
}

__global__ void k_fail(float* out, float v) {
  if (threadIdx.x == 0 && blockIdx.x == 0) out[0] = v;
}

extern "C" void kernel_launch(void* const* d_in, const int* in_sizes, int n_in,
                              void* d_out, int out_size, void* d_ws, size_t ws_size,
                              hipStream_t stream) {
  const float* x   = (const float*)d_in[0];
  const float* h0  = (const float*)d_in[1];
  const float* Wih = (const float*)d_in[2];
  const float* Whh = (const float*)d_in[3];
  const float* bih = (const float*)d_in[4];
  const float* bhh = (const float*)d_in[5];
  float* out = (float*)d_out;

  const size_t GI_BYTES  = (size_t)32768 * 3072 * 2;  // 201,326,592
  const size_t HB_BYTES  = (size_t)2 * 65536 * 2;     // 262,144
  const size_t BAR_BYTES = 4096 * 4;                  // 16,384
  if (ws_size < GI_BYTES + HB_BYTES + BAR_BYTES) {
    k_fail<<<1, 64, 0, stream>>>(out, (float)ws_size);
    return;
  }
  char* ws = (char*)d_ws;
  bf16* gi = (bf16*)ws;
  bf16* hbuf = (bf16*)(ws + GI_BYTES);
  u32* flags = (u32*)(ws + GI_BYTES + HB_BYTES);

  k_init<<<256, 256, 0, stream>>>(h0, hbuf, flags);
  k_gemm<<<6144, 256, 0, stream>>>(x, Wih, bih, gi);
  k_rnn<<<64, 256, 0, stream>>>(h0, Whh, bhh, gi, hbuf, out, flags);
}

// Round 21
// 2888.737 us; speedup vs baseline: 1.0379x; 1.0379x over previous
//
#include <hip/hip_runtime.h>
#include <hip/hip_bf16.h>

// GRU: B=64, S=512, I=1024, H=1024, fp32 in/out, final h only.
// FINAL (round 21) = round-19 verbatim, the best deterministic green:
//   - k_gemm: 128x128 MFMA tile, XCD-aware swizzle (~420us)
//   - k_rnn: 64 WGs x 4 interleaved batch-group phases; W_hh in registers;
//     sc0sc1 h exchange; per-WG flag signal + preload@phase-start + fallback
//     poll; per-wave vmcnt(0) BEFORE sync#1 (the r12 invariant that makes
//     the deferred signal sound for ALL waves); plds double-buffered by grp
//     parity (barrier #3 deleted).
// Session: 5.23ms -> 2.89ms (1.81x). Remaining time is the inter-WG
// communication latency floor (~1.2us/phase) on the GRU's serial chain,
// not a HW bandwidth/compute roofline.

#define B_ 64
#define S_ 512
#define H_ 1024

typedef __bf16 bf16;
typedef __bf16 bf16x8 __attribute__((ext_vector_type(8)));
typedef float  f32x4  __attribute__((ext_vector_type(4)));
typedef unsigned int u32;

__device__ __forceinline__ void ld_cc16(const bf16* p, f32x4* dst) {
  asm volatile("global_load_dwordx4 %0, %1, off sc0 sc1" : "=v"(*dst) : "v"(p));
}
__device__ __forceinline__ void ld_u16(const bf16* p, u32* dst) {
  asm volatile("global_load_ushort %0, %1, off" : "=v"(*dst) : "v"(p));
}
__device__ __forceinline__ void st_cc16(bf16* p, u32 bits) {
  asm volatile("global_store_short %0, %1, off sc0 sc1" :: "v"(p), "v"(bits) : "memory");
}

// ---------------- init: zero flags, pack h0 into hbuf[0] --------------------
__global__ void k_init(const float* __restrict__ h0, bf16* __restrict__ hbuf,
                       u32* __restrict__ flags) {
  int t = blockIdx.x * 256 + threadIdx.x;
  if (t < 4096) flags[t] = 0u;
  if (t < B_ * H_) {
    int b = t >> 10, j = t & 1023;
    hbuf[((size_t)((j >> 3) * 64 + b)) * 8 + (j & 7)] = (bf16)h0[t];
  }
}

// ---------------- gi GEMM: [32768,1024] x [1024,3072] -> bf16 ---------------
__global__ __launch_bounds__(256) void k_gemm(const float* __restrict__ X,
                                              const float* __restrict__ W,
                                              const float* __restrict__ bias,
                                              bf16* __restrict__ gi) {
  __shared__ bf16 As[128 * 40];
  __shared__ bf16 Bs[128 * 40];
  const int tid = threadIdx.x;
  const int bid = (blockIdx.x % 8) * 768 + (blockIdx.x / 8);  // XCD swizzle
  const int bidn = bid % 24, bidm = bid / 24;
  const int row = tid >> 1, half = tid & 1;
  const float* ax = X + (size_t)(bidm * 128 + row) * 1024 + half * 16;
  const float* bw = W + (size_t)(bidn * 128 + row) * 1024 + half * 16;
  const int lane = tid & 63, wave = tid >> 6;
  const int wm = wave >> 1, wn = wave & 1;

  f32x4 acc[4][4];
#pragma unroll
  for (int i = 0; i < 4; ++i)
#pragma unroll
    for (int j = 0; j < 4; ++j) acc[i][j] = (f32x4){0.f, 0.f, 0.f, 0.f};

  for (int ks = 0; ks < 32; ++ks) {
    {
      const float* pa = ax + ks * 32;
      f32x4 a0 = *(const f32x4*)(pa);
      f32x4 a1 = *(const f32x4*)(pa + 4);
      f32x4 a2 = *(const f32x4*)(pa + 8);
      f32x4 a3 = *(const f32x4*)(pa + 12);
      bf16x8 v0, v1;
#pragma unroll
      for (int i = 0; i < 4; ++i) {
        v0[i] = (bf16)a0[i]; v0[4 + i] = (bf16)a1[i];
        v1[i] = (bf16)a2[i]; v1[4 + i] = (bf16)a3[i];
      }
      *(bf16x8*)&As[row * 40 + half * 16]     = v0;
      *(bf16x8*)&As[row * 40 + half * 16 + 8] = v1;

      const float* pb = bw + ks * 32;
      f32x4 b0 = *(const f32x4*)(pb);
      f32x4 b1 = *(const f32x4*)(pb + 4);
      f32x4 b2 = *(const f32x4*)(pb + 8);
      f32x4 b3 = *(const f32x4*)(pb + 12);
#pragma unroll
      for (int i = 0; i < 4; ++i) {
        v0[i] = (bf16)b0[i]; v0[4 + i] = (bf16)b1[i];
        v1[i] = (bf16)b2[i]; v1[4 + i] = (bf16)b3[i];
      }
      *(bf16x8*)&Bs[row * 40 + half * 16]     = v0;
      *(bf16x8*)&Bs[row * 40 + half * 16 + 8] = v1;
    }
    __syncthreads();
    bf16x8 af[4], bfr[4];
#pragma unroll
    for (int mi = 0; mi < 4; ++mi)
      af[mi] = *(const bf16x8*)&As[(wm * 64 + mi * 16 + (lane & 15)) * 40 + (lane >> 4) * 8];
#pragma unroll
    for (int ni = 0; ni < 4; ++ni)
      bfr[ni] = *(const bf16x8*)&Bs[(wn * 64 + ni * 16 + (lane & 15)) * 40 + (lane >> 4) * 8];
#pragma unroll
    for (int mi = 0; mi < 4; ++mi)
#pragma unroll
      for (int ni = 0; ni < 4; ++ni)
        acc[mi][ni] = __builtin_amdgcn_mfma_f32_16x16x32_bf16(af[mi], bfr[ni], acc[mi][ni], 0, 0, 0);
    __syncthreads();
  }

  float bv[4];
#pragma unroll
  for (int ni = 0; ni < 4; ++ni)
    bv[ni] = bias[bidn * 128 + wn * 64 + ni * 16 + (lane & 15)];
#pragma unroll
  for (int mi = 0; mi < 4; ++mi)
#pragma unroll
    for (int ni = 0; ni < 4; ++ni)
#pragma unroll
      for (int r = 0; r < 4; ++r) {
        int grow = bidm * 128 + wm * 64 + mi * 16 + (lane >> 4) * 4 + r;
        int gcol = bidn * 128 + wn * 64 + ni * 16 + (lane & 15);
        gi[(size_t)grow * 3072 + gcol] = (bf16)(acc[mi][ni][r] + bv[ni]);
      }
}

// ---------------- persistent recurrent kernel -------------------------------
__global__ __launch_bounds__(256, 1) void k_rnn(
    const float* __restrict__ h0, const float* __restrict__ Whh,
    const float* __restrict__ bhh, const bf16* __restrict__ gi,
    bf16* __restrict__ hbuf, float* __restrict__ out, u32* __restrict__ flags) {
  __shared__ bf16 wlds[128 * 49 * 8];   // staging; K-loop never reads it
  __shared__ float plds[2 * 3072];      // double-buffered by grp parity
  __shared__ float hold[4][256];        // f32 local h per group

  const int tid = threadIdx.x;
  const int Q = blockIdx.x;                // unit block
  const int lane = tid & 63, wave = tid >> 6;
  const int b = tid >> 4, u = tid & 15;

  for (int idx = tid; idx < 48 * 128; idx += 256) {
    int c = idx % 48, k8 = idx / 48;
    int ga = c >> 4, un = c & 15;
    const float* src = Whh + (size_t)(ga * 1024 + Q * 16 + un) * 1024 + k8 * 8;
    bf16x8 v;
#pragma unroll
    for (int e = 0; e < 8; ++e) v[e] = (bf16)src[e];
    *(bf16x8*)&wlds[(size_t)(k8 * 49 + c) * 8] = v;
  }
#pragma unroll
  for (int g = 0; g < 4; ++g)
    hold[g][tid] = h0[(size_t)(g * 16 + b) * 1024 + Q * 16 + u];
  const float bh0 = bhh[Q * 16 + u];
  const float bh1 = bhh[1024 + Q * 16 + u];
  const float bh2 = bhh[2048 + Q * 16 + u];

  const bf16* giB = gi + (size_t)b * (512 * 3072) + Q * 16 + u;
  const size_t GSTR = (size_t)16 * 512 * 3072;
  const int aoff0 = ((wave * 32 + (lane >> 4)) * 64 + (lane & 15)) * 8;
  const int jj = Q * 16 + u;
  const int hoff0 = ((jj >> 3) * 64 + b) * 8 + (jj & 7);

  __syncthreads();

  // W fragments -> registers (proven round 8)
  bf16x8 wreg[24];
#pragma unroll
  for (int kk = 0; kk < 8; ++kk) {
    int k8 = wave * 32 + kk * 4 + (lane >> 4);
    const bf16* wb = &wlds[(size_t)(k8 * 49 + (lane & 15)) * 8];
    wreg[kk * 3 + 0] = *(const bf16x8*)(wb);
    wreg[kk * 3 + 1] = *(const bf16x8*)(wb + 16 * 8);
    wreg[kk * 3 + 2] = *(const bf16x8*)(wb + 32 * 8);
  }

  f32x4 aff[8];
  u32 gc0, gc1, gc2, gn0, gn1, gn2;
  {
    const bf16* ab = hbuf + aoff0;   // buffer 0, grp 0
#pragma unroll
    for (int kk = 0; kk < 8; ++kk) ld_cc16(ab + kk * 2048, &aff[kk]);
    ld_u16(giB, &gc0); ld_u16(giB + 1024, &gc1); ld_u16(giB + 2048, &gc2);
  }

  int bad = 0;
  for (int t = 0; t < 512; ++t) {
    bf16* curb = hbuf + (size_t)(t & 1) * 65536;
    bf16* nxtb = hbuf + (size_t)((t & 1) ^ 1) * 65536;
    for (int grp = 0; grp < 4; ++grp) {
      const int pb = (grp & 1) * 3072;   // plds buffer for this phase
      if (t == 0 && grp == 0) { asm volatile("s_waitcnt vmcnt(0)" ::: "memory"); }
      else                    { asm volatile("s_waitcnt vmcnt(4)" ::: "memory"); }
      __builtin_amdgcn_sched_barrier(0);

      // preload at phase start (r16); drained by the pre-sync vmcnt(0)
      const bool has_next = !(t == 511 && grp == 3);
      const int ng = (grp + 1) & 3;
      const u32 tn = (u32)((grp < 3) ? t : t + 1);
      u32 fpre = 0xFFFFFFFFu;
      if (has_next && tn && tid < 64) {
        const u32* fp = flags + (ng * 64 + lane) * 16;
        asm volatile("global_load_dword %0, %1, off sc0 sc1" : "=v"(fpre) : "v"(fp));
      }

      f32x4 acc0 = (f32x4){0.f,0.f,0.f,0.f};
      f32x4 acc1 = (f32x4){0.f,0.f,0.f,0.f};
      f32x4 acc2 = (f32x4){0.f,0.f,0.f,0.f};
#pragma unroll
      for (int kk = 0; kk < 8; ++kk) {
        bf16x8 a = __builtin_bit_cast(bf16x8, aff[kk]);
        acc0 = __builtin_amdgcn_mfma_f32_16x16x32_bf16(a, wreg[kk * 3 + 0], acc0, 0, 0, 0);
        acc1 = __builtin_amdgcn_mfma_f32_16x16x32_bf16(a, wreg[kk * 3 + 1], acc1, 0, 0, 0);
        acc2 = __builtin_amdgcn_mfma_f32_16x16x32_bf16(a, wreg[kk * 3 + 2], acc2, 0, 0, 0);
      }
      {
        int prow = wave * 16 + (lane >> 4) * 4;
#pragma unroll
        for (int r = 0; r < 4; ++r) {
          plds[pb + (prow + r) * 48 + (lane & 15)]      = acc0[r];
          plds[pb + (prow + r) * 48 + 16 + (lane & 15)] = acc1[r];
          plds[pb + (prow + r) * 48 + 32 + (lane & 15)] = acc2[r];
        }
      }
      // r12 invariant: per-wave drain BEFORE the barrier
      asm volatile("s_waitcnt vmcnt(0)" ::: "memory");
      __builtin_amdgcn_sched_barrier(0);
      __syncthreads();   // #1: all waves drained => deferred signal is sound

      {
        int sg = (grp + 3) & 3;
        int st_ = (grp == 0) ? t - 1 : t;
        if (tid == 0 && st_ >= 0 && st_ < 511)
          __hip_atomic_store(&flags[(sg * 64 + Q) * 16], (u32)(st_ + 1),
                             __ATOMIC_RELAXED, __HIP_MEMORY_SCOPE_AGENT);
        if (has_next && tn && tid < 64) {
          asm volatile("" : "+v"(fpre));   // launder: order after the drain
          if (!__all(fpre >= tn)) {
            const u32* fp = flags + (ng * 64 + lane) * 16;
            int guard = 0;
            while (1) {
              u32 f = __hip_atomic_load(fp, __ATOMIC_RELAXED,
                                        __HIP_MEMORY_SCOPE_AGENT);
              if (__all(f >= tn)) break;
              if (++guard > (1 << 16)) { bad = 1; break; }
              __builtin_amdgcn_s_sleep(1);
            }
          }
        }
      }
      __builtin_amdgcn_s_barrier();   // #2 raw: release poll result

      if (has_next) {
        const bf16* ab = ((grp < 3) ? curb : nxtb) + aoff0 + ng * 128;
#pragma unroll
        for (int kk = 0; kk < 8; ++kk) ld_cc16(ab + kk * 2048, &aff[kk]);
        int ntp = (grp < 3) ? t : t + 1;
        const bf16* p = giB + (size_t)ng * GSTR + (size_t)ntp * 3072;
        ld_u16(p, &gn0); ld_u16(p + 1024, &gn1); ld_u16(p + 2048, &gn2);
      }

      float ghr = bh0, ghz = bh1, ghn = bh2;
#pragma unroll
      for (int w = 0; w < 4; ++w) {
        ghr += plds[pb + w * 768 + b * 48 + u];
        ghz += plds[pb + w * 768 + b * 48 + 16 + u];
        ghn += plds[pb + w * 768 + b * 48 + 32 + u];
      }
      float gir = __builtin_bit_cast(float, gc0 << 16);
      float giz = __builtin_bit_cast(float, gc1 << 16);
      float gin = __builtin_bit_cast(float, gc2 << 16);
      float rg = 1.f / (1.f + __expf(-(gir + ghr)));
      float zg = 1.f / (1.f + __expf(-(giz + ghz)));
      float e2 = __expf(2.f * (gin + rg * ghn));
      float tng = 1.f - 2.f / (e2 + 1.f);
      float hnew = (1.f - zg) * tng + zg * hold[grp][tid];
      hold[grp][tid] = hnew;
      if (t == 511) {
        if (bad) hnew = 12345.0f;   // stall signature
        out[(size_t)(grp * 16 + b) * 1024 + jj] = hnew;
      } else {
        unsigned short hb = __builtin_bit_cast(unsigned short, (bf16)hnew);
        st_cc16(nxtb + hoff0 + grp * 128, (u32)hb);
      }
      gc0 = gn0; gc1 = gn1; gc2 = gn2;
      // barrier #3 deleted (r19): next phase writes the other plds buffer;
      // the 2-phase-distant reuse is fenced by the intervening sync#1.
    }
  }
}

__global__ void k_fail(float* out, float v) {
  if (threadIdx.x == 0 && blockIdx.x == 0) out[0] = v;
}

extern "C" void kernel_launch(void* const* d_in, const int* in_sizes, int n_in,
                              void* d_out, int out_size, void* d_ws, size_t ws_size,
                              hipStream_t stream) {
  const float* x   = (const float*)d_in[0];
  const float* h0  = (const float*)d_in[1];
  const float* Wih = (const float*)d_in[2];
  const float* Whh = (const float*)d_in[3];
  const float* bih = (const float*)d_in[4];
  const float* bhh = (const float*)d_in[5];
  float* out = (float*)d_out;

  const size_t GI_BYTES  = (size_t)32768 * 3072 * 2;  // 201,326,592
  const size_t HB_BYTES  = (size_t)2 * 65536 * 2;     // 262,144
  const size_t BAR_BYTES = 4096 * 4;                  // 16,384
  if (ws_size < GI_BYTES + HB_BYTES + BAR_BYTES) {
    k_fail<<<1, 64, 0, stream>>>(out, (float)ws_size);
    return;
  }
  char* ws = (char*)d_ws;
  bf16* gi = (bf16*)ws;
  bf16* hbuf = (bf16*)(ws + GI_BYTES);
  u32* flags = (u32*)(ws + GI_BYTES + HB_BYTES);

  k_init<<<256, 256, 0, stream>>>(h0, hbuf, flags);
  k_gemm<<<6144, 256, 0, stream>>>(x, Wih, bih, gi);
  k_rnn<<<64, 256, 0, stream>>>(h0, Whh, bhh, gi, hbuf, out, flags);
}